// Round 2
// baseline (243.499 us; speedup 1.0000x reference)
//
#include <hip/hip_runtime.h>

// out[n, t] = sum_{j <= t} W[t, j] * x[n, j] + b[t]
// B = 1048576, T = 32, fp32 in/out. HBM floor: 256 MB @ ~6.3 TB/s -> ~41 us.
//
// R2: pad-33 LDS (all-scalar ds ops, 128 b32/thread) replaced by XOR-swizzled
// float4 layout: chunk (row,c) at slot row*8 + (c ^ (row&7)).
//  - stage-in: global_load_lds width=16, linear LDS dest + pre-swizzled global
//    source (per-lane addr), no VGPR round-trip, no ds_writes.
//  - row reads / writeback / out-reads: ds_read/write_b128, full LDS BW,
//    conflict-free (slot%8 = k^(row&7) covers 0..7 in every wave).
//  - LDS 33792 -> 32768 B: 5 blocks/CU (was 4).
// W/b stay scalar (s_load -> SGPR FMA operand; verified R1: VALUBusy 23->10.6).

constexpr int T    = 32;
constexpr int ROWS = 256;          // rows per block == block size (1 thread per row)

__global__ __launch_bounds__(256) void triu_kernel(
    const float* __restrict__ x, const float* __restrict__ W,
    const float* __restrict__ b, float* __restrict__ out)
{
    __shared__ float4 sX[ROWS * 8];    // 32 KiB exactly -> 5 blocks/CU

    const int tid  = threadIdx.x;
    const int lane = tid & 63;
    const int wid  = tid >> 6;
    const long long base4 = (long long)blockIdx.x * (ROWS * 8);   // float4 units

    const float4* __restrict__ x4 = reinterpret_cast<const float4*>(x) + base4;

    // Stage-in: linear LDS slots (wave-uniform base + lane*16), global source
    // pre-swizzled so slot s receives chunk (row = s>>3, c = (s&7)^(row&7)).
    // Global addrs per instr cover a contiguous 1 KiB span (permuted within
    // rows) -> fully coalesced.
    #pragma unroll
    for (int it = 0; it < 8; ++it) {
        const int s   = it * 256 + wid * 64 + lane;
        const int row = s >> 3;
        const int c   = (s & 7) ^ (row & 7);
        __builtin_amdgcn_global_load_lds(
            (const __attribute__((address_space(1))) void*)(x4 + row * 8 + c),
            (__attribute__((address_space(3))) void*)(&sX[it * 256 + wid * 64]),
            16, 0, 0);
    }
    __syncthreads();   // compiler drains vmcnt before s_barrier

    // This thread's row: 8 x ds_read_b128, swizzle-inverted (XOR is involutive).
    const int r7 = tid & 7;
    float xr[T];
    #pragma unroll
    for (int k = 0; k < 8; ++k) {
        const float4 v = sX[tid * 8 + (k ^ r7)];
        xr[4 * k + 0] = v.x; xr[4 * k + 1] = v.y;
        xr[4 * k + 2] = v.z; xr[4 * k + 3] = v.w;
    }

    // Triangular FMA; W[t*T+j] / b[t] wave-uniform -> scalar loads, SGPR operand.
    float acc[T];
    #pragma unroll
    for (int t = 0; t < T; ++t) {
        float a = b[t];
        #pragma unroll
        for (int j = 0; j <= t; ++j)
            a = fmaf(W[t * T + j], xr[j], a);
        acc[t] = a;
    }

    // Writeback own row (only this thread read these slots -> no pre-barrier).
    #pragma unroll
    for (int k = 0; k < 8; ++k)
        sX[tid * 8 + (k ^ r7)] = make_float4(acc[4 * k + 0], acc[4 * k + 1],
                                             acc[4 * k + 2], acc[4 * k + 3]);
    __syncthreads();

    // Stage-out: swizzled ds_read_b128 -> coalesced float4 global stores.
    float4* __restrict__ o4 = reinterpret_cast<float4*>(out) + base4;
    #pragma unroll
    for (int it = 0; it < 8; ++it) {
        const int idx = it * 256 + tid;
        const int row = idx >> 3;
        o4[idx] = sX[row * 8 + ((idx & 7) ^ (row & 7))];
    }
}

extern "C" void kernel_launch(void* const* d_in, const int* in_sizes, int n_in,
                              void* d_out, int out_size, void* d_ws, size_t ws_size,
                              hipStream_t stream) {
    const float* x  = (const float*)d_in[0];   // [B, 32]
    const float* W  = (const float*)d_in[1];   // [32, 32] (lower-tri used)
    const float* b  = (const float*)d_in[2];   // [32]
    float* out      = (float*)d_out;           // [B, 32]

    const int batch = in_sizes[0] / T;         // 1048576
    const int grid  = batch / ROWS;            // 4096 blocks
    triu_kernel<<<grid, 256, 0, stream>>>(x, W, b, out);
}